// Round 6
// baseline (240.844 us; speedup 1.0000x reference)
//
#include <hip/hip_runtime.h>
#include <stdint.h>

// Self-attention, B=8 S=2048 D=E=512, fp32 in/out, bf16 MFMA internally.
//   xconv:    x fp32 -> bf16
//   wconv:    W[k][n] fp32 -> Wt[n][k] bf16 (x3), LDS-tiled transpose
//   qkv_gemm: v2 PIPELINED: As/Bs double-buffered, stage(it+1) issued BEFORE
//             compute(it), ONE barrier/iter -> staging latency hidden under MFMA
//             (was: issue->immediate vmcnt(0) drain = full latency exposed 8x/block).
//   attn:     v6 (unchanged, measured 125.3 µs): counted-vmcnt pipeline, Kt triple-
//             buffered, Pl double-buffered, one fused barrier/iter, setprio.

using f32x4 = __attribute__((ext_vector_type(4))) float;
using s16x8 = __attribute__((ext_vector_type(8))) short;
using u16x4 = __attribute__((ext_vector_type(4))) unsigned short;

#define S_LEN 2048
#define EMB   512

#define ASYNC16(g, l)                                                     \
  __builtin_amdgcn_global_load_lds(                                       \
      (const __attribute__((address_space(1))) void*)(g),                 \
      (__attribute__((address_space(3))) void*)(l), 16, 0, 0)

__device__ __forceinline__ unsigned short f2bf(float f) {
  union { float f; unsigned u; } v; v.f = f;
  unsigned r = v.u + 0x7fffu + ((v.u >> 16) & 1u);   // RNE
  return (unsigned short)(r >> 16);
}

// ---------------- kernel 0: x fp32 -> bf16 ----------------
__global__ __launch_bounds__(256) void xconv_kernel(
    const float* __restrict__ x, short* __restrict__ xb) {
  int i = (blockIdx.x * 256 + threadIdx.x) * 8;
  f32x4 a = *(const f32x4*)(x + i);
  f32x4 b = *(const f32x4*)(x + i + 4);
  s16x8 h;
  h[0] = (short)f2bf(a[0]); h[1] = (short)f2bf(a[1]);
  h[2] = (short)f2bf(a[2]); h[3] = (short)f2bf(a[3]);
  h[4] = (short)f2bf(b[0]); h[5] = (short)f2bf(b[1]);
  h[6] = (short)f2bf(b[2]); h[7] = (short)f2bf(b[3]);
  *(s16x8*)(xb + i) = h;
}

// ---------------- kernel 1: weight transpose (LDS-tiled, coalesced) ----------------
__global__ __launch_bounds__(256) void wconv_kernel(
    const float* __restrict__ Wq, const float* __restrict__ Wk,
    const float* __restrict__ Wv, short* __restrict__ Wt) {
  __shared__ float T[64][65];
  int bid = blockIdx.x;
  int mat = bid >> 6;
  int t   = bid & 63;
  int k0  = (t & 7) << 6, n0 = (t >> 3) << 6;
  const float* W = (mat == 0) ? Wq : (mat == 1) ? Wk : Wv;
  int tid = threadIdx.x;
  int rr = tid >> 4, cc = tid & 15;
#pragma unroll
  for (int p = 0; p < 4; ++p) {
    int row = p * 16 + rr;
    f32x4 v = *(const f32x4*)(W + (size_t)(k0 + row) * 512 + n0 + cc * 4);
#pragma unroll
    for (int j = 0; j < 4; ++j) T[row][cc * 4 + j] = v[j];
  }
  __syncthreads();
  short* D = Wt + (size_t)mat * 262144;
#pragma unroll
  for (int p = 0; p < 4; ++p) {
    int nrow = p * 16 + rr;
    u16x4 h;
#pragma unroll
    for (int j = 0; j < 4; ++j) h[j] = f2bf(T[cc * 4 + j][nrow]);
    *(u16x4*)(D + (size_t)(n0 + nrow) * 512 + k0 + cc * 4) = h;
  }
}

// ---------------- kernel 2: QKV projection GEMM v2 (pipelined staging) ----------------
// Per-iter: stage(it+1) -> buf^1 (8 ASYNC16/wave, fire-and-forget), compute(it) from
// buf (16 ds_read_b128 + 32 MFMA/wave), ONE __syncthreads (vmcnt(0) drains stage(it+1)
// which had the whole compute phase to land).
// Ledger: RAW stage(it)->compute(it): stage(it) issued pre-barrier(it-1), drained there.
//         WAR stage(it+1) vs compute(it-1) readers of buf^1: separated by barrier(it-1).
__global__ __launch_bounds__(256) void qkv_gemm(
    const short* __restrict__ xb, const short* __restrict__ Wt,
    const float* __restrict__ bq, const float* __restrict__ bk,
    const float* __restrict__ bv,
    short* __restrict__ Qg, short* __restrict__ Kg, short* __restrict__ VTg) {
  __shared__ __align__(16) short As[2][128 * 64];   // 16B chunk c stored at c^(row&7)
  __shared__ __align__(16) short Bs[2][128 * 64];
  int gid = blockIdx.x;
  int mat = gid >> 9;
  int rem = gid & 511;
  int mt  = rem & 127, nt = rem >> 7;
  int m0  = mt << 7,   n0 = nt << 7;
  const short* W    = Wt + (size_t)mat * 262144;
  const float* bias = (mat == 0) ? bq : (mat == 1) ? bk : bv;

  int tid = threadIdx.x, lane = tid & 63, wv = tid >> 6;
  int l16 = lane & 15, quad = lane >> 4;
  int wr = (wv & 1) << 6, wc = (wv >> 1) << 6;
  int drow = lane >> 3;
  int dchk = (lane & 7) ^ drow;

  // per-wave staging source bases (row = wv*32 + i*8 + drow for i=0..3)
  const short* asrc[4];
  const short* bsrc[4];
#pragma unroll
  for (int i = 0; i < 4; ++i) {
    int row = (wv * 4 + i) * 8 + drow;
    asrc[i] = xb + (size_t)(m0 + row) * 512 + dchk * 8;
    bsrc[i] = W  + (size_t)(n0 + row) * 512 + dchk * 8;
  }

  const f32x4 Z4 = {0.f, 0.f, 0.f, 0.f};
  f32x4 acc[4][4];
#pragma unroll
  for (int a = 0; a < 4; ++a)
#pragma unroll
    for (int c = 0; c < 4; ++c) acc[a][c] = Z4;

  // ---- prologue: stage it=0 into buf 0 ----
#pragma unroll
  for (int i = 0; i < 4; ++i) {
    int g = wv * 4 + i;
    ASYNC16(asrc[i], &As[0][g * 512]);
    ASYNC16(bsrc[i], &Bs[0][g * 512]);
  }
  __syncthreads();   // drain stage(0)

  for (int it = 0; it < 8; ++it) {
    int buf = it & 1;
    // ---- stage it+1 into buf^1 (latency hidden under compute below) ----
    if (it < 7) {
      int k1 = (it + 1) << 6;
#pragma unroll
      for (int i = 0; i < 4; ++i) {
        int g = wv * 4 + i;
        ASYNC16(asrc[i] + k1, &As[buf ^ 1][g * 512]);
        ASYNC16(bsrc[i] + k1, &Bs[buf ^ 1][g * 512]);
      }
    }
    // ---- compute from buf ----
#pragma unroll
    for (int kk = 0; kk < 2; ++kk) {
      s16x8 af[4], bfr[4];
#pragma unroll
      for (int rb = 0; rb < 4; ++rb) {
        int row = wr + rb * 16 + l16;
        int c   = kk * 4 + quad;
        af[rb] = *(const s16x8*)(&As[buf][row * 64 + ((c ^ (row & 7)) * 8)]);
      }
#pragma unroll
      for (int cb = 0; cb < 4; ++cb) {
        int row = wc + cb * 16 + l16;
        int c   = kk * 4 + quad;
        bfr[cb] = *(const s16x8*)(&Bs[buf][row * 64 + ((c ^ (row & 7)) * 8)]);
      }
#pragma unroll
      for (int rb = 0; rb < 4; ++rb)
#pragma unroll
        for (int cb = 0; cb < 4; ++cb)
          acc[rb][cb] = __builtin_amdgcn_mfma_f32_16x16x32_bf16(af[rb], bfr[cb], acc[rb][cb], 0, 0, 0);
    }
    __syncthreads();   // drains stage(it+1); separates buf^1 WAR
  }

  float bsv[4];
#pragma unroll
  for (int cb = 0; cb < 4; ++cb) bsv[cb] = bias[n0 + wc + cb * 16 + l16];

  if (mat < 2) {
    short* D = (mat == 0) ? Qg : Kg;
#pragma unroll
    for (int rb = 0; rb < 4; ++rb)
#pragma unroll
      for (int cb = 0; cb < 4; ++cb)
#pragma unroll
        for (int r = 0; r < 4; ++r) {
          int m = m0 + wr + rb * 16 + quad * 4 + r;
          D[(size_t)m * 512 + n0 + wc + cb * 16 + l16] =
              (short)f2bf(acc[rb][cb][r] + bsv[cb]);
        }
  } else {
    // V: tiled transpose layout [bb][e>>4][s>>5][e&15][s&31], 1KB tiles
#pragma unroll
    for (int rb = 0; rb < 4; ++rb)
#pragma unroll
      for (int cb = 0; cb < 4; ++cb) {
        u16x4 h;
#pragma unroll
        for (int r = 0; r < 4; ++r) h[r] = f2bf(acc[rb][cb][r] + bsv[cb]);
        int m  = m0 + wr + rb * 16 + quad * 4;
        int bb = m >> 11, sl = m & 2047;
        int e  = n0 + wc + cb * 16 + l16;
        size_t idx = ((((size_t)bb * 32 + (e >> 4)) * 64 + (sl >> 5)) * 16 +
                      (e & 15)) * 32 + (sl & 31);
        *(u16x4*)(VTg + idx) = h;
      }
  }
}

// ---------------- kernel 3: flash attention v6 (counted-vmcnt pipeline) ----------------
// UNCHANGED from round 5 (measured 125.3 µs, passed).
__global__ __launch_bounds__(512, 2) void attn_kernel(
    const short* __restrict__ Qg, const short* __restrict__ Kg,
    const short* __restrict__ VTg, float* __restrict__ out) {
  __shared__ __align__(16) short Kt[3][32 * 512];   // 96 KB triple buffer
  __shared__ __align__(16) short Pl[2][64 * 40];    // 10 KB double buffer
  __shared__ float l_l[64];
  const float SCL2 = 0.06375871855f;  // log2(e)/sqrt(512)

  int b = blockIdx.x & 7, qt = blockIdx.x >> 3;   // qt 0..31
  int s0 = qt << 6;                                // 64 rows/block
  int tid = threadIdx.x, lane = tid & 63, wv = tid >> 6;  // wv 0..7
  int l16 = lane & 15, quad = lane >> 4;
  int a = wv & 3, h = wv >> 2;
  int e0 = wv << 6;

  const short* Kb = Kg  + (size_t)b * S_LEN * 512;
  const short* Vb = VTg + (size_t)b * 1048576;     // [32 et][64 st][16][32]

  const short* kdma[4];
#pragma unroll
  for (int i = 0; i < 4; ++i) {
    int r = wv * 4 + i;
    kdma[i] = Kb + (size_t)r * 512 + ((lane ^ (r & 7)) * 8);
  }
  const short* vbase = Vb + (size_t)wv * 131072 + l16 * 32 + quad * 8;

#pragma unroll
  for (int i = 0; i < 4; ++i)
    ASYNC16(kdma[i], &Kt[0][(wv * 4 + i) * 512]);
#pragma unroll
  for (int i = 0; i < 4; ++i)
    ASYNC16(kdma[i] + 16384, &Kt[1][(wv * 4 + i) * 512]);

  const short* qrow = Qg + ((size_t)b * S_LEN + s0 + a * 16 + l16) * 512 + quad * 8;
  s16x8 qf[16];
#pragma unroll
  for (int kk = 0; kk < 16; ++kk) qf[kk] = *(const s16x8*)(qrow + kk * 32);

  const f32x4 Z4 = {0.f, 0.f, 0.f, 0.f};
  f32x4 acc[4][4];
#pragma unroll
  for (int rb = 0; rb < 4; ++rb)
#pragma unroll
    for (int cb = 0; cb < 4; ++cb) acc[rb][cb] = Z4;
  f32x4 lsum = Z4;

  __syncthreads();   // prologue full drain (one-time): K0,K1 + Q landed

  int rbuf = 0, wbuf = 2;
  for (int kt = 0; kt < 64; ++kt) {
    s16x8 vf[4];
#pragma unroll
    for (int cb = 0; cb < 4; ++cb)
      vf[cb] = *(const s16x8*)(vbase + (size_t)cb * 32768 + (size_t)kt * 512);
    __builtin_amdgcn_sched_barrier(0);

    {
      size_t adv = (size_t)((kt + 2) & 63) * 16384;
#pragma unroll
      for (int i = 0; i < 4; ++i)
        ASYNC16(kdma[i] + adv, &Kt[wbuf][(wv * 4 + i) * 512]);
    }
    __builtin_amdgcn_sched_barrier(0);

    f32x4 s_a = Z4, s_b = Z4;
    int krow = h * 16 + l16;
    const short* kb = &Kt[rbuf][krow * 512];
    int ksw = krow & 7;
    __builtin_amdgcn_s_setprio(1);
#pragma unroll
    for (int kk = 0; kk < 8; ++kk) {
      s16x8 kf0 = *(const s16x8*)(kb + (((2 * kk) * 4 + quad) ^ ksw) * 8);
      s_a = __builtin_amdgcn_mfma_f32_16x16x32_bf16(qf[2 * kk], kf0, s_a, 0, 0, 0);
      s16x8 kf1 = *(const s16x8*)(kb + (((2 * kk + 1) * 4 + quad) ^ ksw) * 8);
      s_b = __builtin_amdgcn_mfma_f32_16x16x32_bf16(qf[2 * kk + 1], kf1, s_b, 0, 0, 0);
    }
    __builtin_amdgcn_s_setprio(0);
    f32x4 sv = s_a + s_b;

    short* Pc = Pl[kt & 1];
#pragma unroll
    for (int r = 0; r < 4; ++r) {
      float p = exp2f(sv[r] * SCL2);
      lsum[r] += p;
      Pc[(a * 16 + quad * 4 + r) * 40 + h * 16 + l16] = (short)f2bf(p);
    }

    asm volatile("s_waitcnt vmcnt(8) lgkmcnt(0)\n\ts_barrier" ::: "memory");

    s16x8 pf[4];
#pragma unroll
    for (int g = 0; g < 4; ++g)
      pf[g] = *(const s16x8*)(Pc + (g * 16 + l16) * 40 + quad * 8);
    __builtin_amdgcn_s_setprio(1);
#pragma unroll
    for (int cb = 0; cb < 4; ++cb)
#pragma unroll
      for (int g = 0; g < 4; ++g)
        acc[g][cb] = __builtin_amdgcn_mfma_f32_16x16x32_bf16(pf[g], vf[cb], acc[g][cb], 0, 0, 0);
    __builtin_amdgcn_s_setprio(0);

    rbuf = (rbuf == 2) ? 0 : rbuf + 1;
    wbuf = (wbuf == 2) ? 0 : wbuf + 1;
  }

#pragma unroll
  for (int r = 0; r < 4; ++r) {
    float v = lsum[r];
    v += __shfl_xor(v, 1);
    v += __shfl_xor(v, 2);
    v += __shfl_xor(v, 4);
    v += __shfl_xor(v, 8);
    lsum[r] = v;
  }
  if (h == 0 && l16 == 0) {
#pragma unroll
    for (int r = 0; r < 4; ++r) l_l[a * 16 + quad * 4 + r] = lsum[r];
  }
  __syncthreads();
  if (h == 1 && l16 == 0) {
#pragma unroll
    for (int r = 0; r < 4; ++r) l_l[a * 16 + quad * 4 + r] += lsum[r];
  }
  __syncthreads();

#pragma unroll
  for (int rb = 0; rb < 4; ++rb) {
    f32x4 lv = *(const f32x4*)(l_l + rb * 16 + quad * 4);
    f32x4 li;
#pragma unroll
    for (int r = 0; r < 4; ++r) li[r] = 1.0f / lv[r];
#pragma unroll
    for (int cb = 0; cb < 4; ++cb)
#pragma unroll
      for (int r = 0; r < 4; ++r)
        out[((size_t)b * S_LEN + s0 + rb * 16 + quad * 4 + r) * 512 + e0 + cb * 16 + l16] =
            acc[rb][cb][r] * li[r];
  }
}

// ---------------- host launch ----------------
extern "C" void kernel_launch(void* const* d_in, const int* in_sizes, int n_in,
                              void* d_out, int out_size, void* d_ws, size_t ws_size,
                              hipStream_t stream) {
  const float* x  = (const float*)d_in[0];
  const float* Wq = (const float*)d_in[1];
  const float* bq = (const float*)d_in[2];
  const float* Wk = (const float*)d_in[3];
  const float* bk = (const float*)d_in[4];
  const float* Wv = (const float*)d_in[5];
  const float* bv = (const float*)d_in[6];

  short* Wt  = (short*)d_ws;
  short* xb  = (short*)((char*)d_ws + 1572864);
  short* Qg  = xb + (size_t)8388608;
  short* Kg  = Qg + (size_t)8388608;
  short* VTg = Kg + (size_t)8388608;

  xconv_kernel<<<4096, 256, 0, stream>>>(x, xb);
  wconv_kernel<<<192, 256, 0, stream>>>(Wq, Wk, Wv, Wt);
  qkv_gemm<<<1536, 256, 0, stream>>>(xb, Wt, bq, bk, bv, Qg, Kg, VTg);
  attn_kernel<<<256, 512, 0, stream>>>(Qg, Kg, VTg, (float*)d_out);
}